// Round 9
// baseline (234.049 us; speedup 1.0000x reference)
//
#include <hip/hip_runtime.h>

// WeightedGCN: 2-layer GCNConv (PyG), N=100K, E=1.25M, D=64, fp32 in/out.
// R18 (base = R17's 230us; k_agg_gemm 51us VALUBusy 60% occ 50%, VGPR stayed
//  40 even with 8 gathers in flight -> R17's (256,8)->(256,6) downgrade of
//  aggregate2 gave away waves for nothing; still latency-bound).
//  Concurrency giveback + uniform loop:
//  (1) k_aggregate2 back to launch_bounds(256,8): VGPR 40 <= 64 cap ->
//      32 waves/CU (+33% outstanding gathers).
//  (2) k_agg_gemm (256,6)->(256,7): cap ~73 >= 40; LDS 21KB x 7 = 147KB fits
//      -> 7 blocks/CU (+17% waves).
//  (3) csr padded to x8 (CAP 10240): 8-edge loop is TAIL-FREE (no divergent
//      tail; 4 groups/wave disagreed ~50% of the time). Pads gather row 0 ->
//      L1-hit after first touch, near-free.
// Rest identical to R17.

typedef unsigned int u32;
typedef unsigned short u16;

#define NBKT 256         // coarse buckets
#define LSH 9            // 512 nodes per bucket
#define BNODES 512
#define CAP 10240        // x8-padded capacity (max cnt ~6800 + 7*512 pads)
#define SRCBITS 17       // N=100K < 2^17
#define SRCMASK ((1u << SRCBITS) - 1u)

__device__ inline u16 f2bf(float f) {            // RNE fp32->bf16
  u32 u = __float_as_uint(f);
  u32 r = u + 0x7FFFu + ((u >> 16) & 1u);
  return (u16)(r >> 16);
}
__device__ inline float bf_lo(u32 p) { return __uint_as_float(p << 16); }
__device__ inline float bf_hi(u32 p) { return __uint_as_float(p & 0xFFFF0000u); }

// block-wide (256 thr) exclusive scan of one u32/thread; wsum = LDS[4] scratch.
__device__ inline u32 blockscan256_excl(u32 val, u32* wsum) {
  int lane = threadIdx.x & 63, wv = threadIdx.x >> 6;
  u32 inc = val;
  #pragma unroll
  for (int d = 1; d < 64; d <<= 1) {
    u32 t = __shfl_up(inc, d);
    if (lane >= d) inc += t;
  }
  if (lane == 63) wsum[wv] = inc;
  __syncthreads();
  u32 off = 0;
  #pragma unroll
  for (int i = 0; i < 4; ++i) if (i < wv) off += wsum[i];
  return off + inc - val;
}

// 4-edge FMA burst: gathers already in registers.
#define AGG4(ha, hb, hc, hd, fa, fb, fc, fd)                                   \
  acc.x = fmaf(bf_lo(ha.x), fa, acc.x); acc.y = fmaf(bf_hi(ha.x), fa, acc.y);  \
  acc.z = fmaf(bf_lo(ha.y), fa, acc.z); acc.w = fmaf(bf_hi(ha.y), fa, acc.w);  \
  acc.x = fmaf(bf_lo(hb.x), fb, acc.x); acc.y = fmaf(bf_hi(hb.x), fb, acc.y);  \
  acc.z = fmaf(bf_lo(hb.y), fb, acc.z); acc.w = fmaf(bf_hi(hb.y), fb, acc.w);  \
  acc.x = fmaf(bf_lo(hc.x), fc, acc.x); acc.y = fmaf(bf_hi(hc.x), fc, acc.y);  \
  acc.z = fmaf(bf_lo(hc.y), fc, acc.z); acc.w = fmaf(bf_hi(hc.y), fc, acc.w);  \
  acc.x = fmaf(bf_lo(hd.x), fd, acc.x); acc.y = fmaf(bf_hi(hd.x), fd, acc.y);  \
  acc.z = fmaf(bf_lo(hd.y), fd, acc.z); acc.w = fmaf(bf_hi(hd.y), fd, acc.w);

// 8-edge gather+FMA body (no tail: n is x8-padded).
#define AGG8_BODY(c4, base)                                                    \
  {                                                                            \
    int4 ca = c4[(base) >> 1];                                                 \
    int4 cb = c4[((base) >> 1) + 1];                                           \
    int4 cc = c4[((base) >> 1) + 2];                                           \
    int4 cd = c4[((base) >> 1) + 3];                                           \
    uint2 h0 = *(const uint2*)(H + (size_t)ca.x * 64 + fid);                   \
    uint2 h1 = *(const uint2*)(H + (size_t)ca.z * 64 + fid);                   \
    uint2 h2 = *(const uint2*)(H + (size_t)cb.x * 64 + fid);                   \
    uint2 h3 = *(const uint2*)(H + (size_t)cb.z * 64 + fid);                   \
    uint2 h4 = *(const uint2*)(H + (size_t)cc.x * 64 + fid);                   \
    uint2 h5 = *(const uint2*)(H + (size_t)cc.z * 64 + fid);                   \
    uint2 h6 = *(const uint2*)(H + (size_t)cd.x * 64 + fid);                   \
    uint2 h7 = *(const uint2*)(H + (size_t)cd.z * 64 + fid);                   \
    float f0 = __int_as_float(ca.y), f1 = __int_as_float(ca.w);                \
    float f2 = __int_as_float(cb.y), f3 = __int_as_float(cb.w);                \
    float f4 = __int_as_float(cc.y), f5 = __int_as_float(cc.w);                \
    float f6 = __int_as_float(cd.y), f7 = __int_as_float(cd.w);                \
    AGG4(h0, h1, h2, h3, f0, f1, f2, f3)                                       \
    AGG4(h4, h5, h6, h7, f4, f5, f6, f7)                                       \
  }

// ---- pass 1: per-block bucket histogram (LDS atomics) + contiguous range
//      reservation (one global atomicAdd per bucket per block). ----
__global__ void k_bin(const int* __restrict__ ei, u32* __restrict__ bucket_cnt,
                      u32* __restrict__ blockbase, int E, int chunk) {
  __shared__ u32 hist[NBKT];
  if (threadIdx.x < NBKT) hist[threadIdx.x] = 0u;
  __syncthreads();
  int e0 = blockIdx.x * chunk;
  int e1 = min(E, e0 + chunk);
  for (int e = e0 + (threadIdx.x << 1); e < e1; e += 512) {
    if (e + 1 < e1) {
      int2 dd = *(const int2*)(ei + E + e);
      atomicAdd(&hist[dd.x >> LSH], 1u);
      atomicAdd(&hist[dd.y >> LSH], 1u);
    } else {
      atomicAdd(&hist[ei[E + e] >> LSH], 1u);
    }
  }
  __syncthreads();
  if (threadIdx.x < NBKT)
    blockbase[threadIdx.x * 256 + blockIdx.x] =
        atomicAdd(&bucket_cnt[threadIdx.x], hist[threadIdx.x]);
}

// ---- pass 2 (+ fused GEMM-1): scatter edges into reserved bucket sub-ranges.
// GEMM branch (blockIdx >= 256): 16 rows/block, X from LDS, register-lean.
// H1 = X @ W1^T -> bf16 UNSCALED (statsfill scales by dis later).
__global__ __launch_bounds__(256, 4) void k_scatter_gemm(
    const int* __restrict__ ei, const float* __restrict__ w,
    const u32* __restrict__ blockbase,
    uint2* __restrict__ bucketed,
    const float* __restrict__ X, const float* __restrict__ W,
    u16* __restrict__ H, int N, int E, int chunk) {
  __shared__ float Wt[64 * 65];
  __shared__ float Xs[16 * 64];
  __shared__ u32 base[NBKT];
  int tid = threadIdx.x;
  if ((int)blockIdx.x < 256) {
    if (tid < NBKT)
      base[tid] = (u32)tid * CAP + blockbase[tid * 256 + blockIdx.x];
    __syncthreads();
    int e0 = blockIdx.x * chunk, e1 = min(E, e0 + chunk);
    for (int e = e0 + (tid << 1); e < e1; e += 512) {
      if (e + 1 < e1) {
        int2 ss = *(const int2*)(ei + e);
        int2 dd = *(const int2*)(ei + E + e);
        float2 wv = *(const float2*)(w + e);
        u32 p0 = atomicAdd(&base[dd.x >> LSH], 1u);
        u32 p1 = atomicAdd(&base[dd.y >> LSH], 1u);
        bucketed[p0] = make_uint2((u32)ss.x | ((u32)(dd.x & (BNODES - 1)) << SRCBITS),
                                  __float_as_uint(wv.x));
        bucketed[p1] = make_uint2((u32)ss.y | ((u32)(dd.y & (BNODES - 1)) << SRCBITS),
                                  __float_as_uint(wv.y));
      } else {
        int s = ei[e], d = ei[E + e];
        u32 pos = atomicAdd(&base[d >> LSH], 1u);
        bucketed[pos] = make_uint2((u32)s | ((u32)(d & (BNODES - 1)) << SRCBITS),
                                   __float_as_uint(w[e]));
      }
    }
    return;
  }
  // ---- GEMM branch ----
  int row0 = ((int)blockIdx.x - 256) * 16;
  if (row0 >= N) return;
  for (int i = tid; i < 4096; i += 256) Wt[(i & 63) * 65 + (i >> 6)] = W[i];
  {
    const float4* xsrc = (const float4*)(X + (size_t)row0 * 64);
    if (row0 + 16 <= N) {
      ((float4*)Xs)[tid] = xsrc[tid];
    } else {
      int r = tid >> 4;
      ((float4*)Xs)[tid] = (row0 + r < N) ? xsrc[tid]
                                          : make_float4(0.f, 0.f, 0.f, 0.f);
    }
  }
  __syncthreads();
  int lane = tid & 63, wv4 = tid >> 6;
  int rbase = wv4 * 4;
  float a0 = 0.f, a1 = 0.f, a2 = 0.f, a3 = 0.f;
  #pragma unroll 4
  for (int k4 = 0; k4 < 16; ++k4) {
    int k = k4 << 2;
    float w0 = Wt[k * 65 + lane], w1 = Wt[(k + 1) * 65 + lane];
    float w2 = Wt[(k + 2) * 65 + lane], w3 = Wt[(k + 3) * 65 + lane];
    float4 xa = *(const float4*)&Xs[(rbase + 0) * 64 + k];
    float4 xb = *(const float4*)&Xs[(rbase + 1) * 64 + k];
    float4 xc = *(const float4*)&Xs[(rbase + 2) * 64 + k];
    float4 xd = *(const float4*)&Xs[(rbase + 3) * 64 + k];
    a0 = fmaf(xa.x, w0, fmaf(xa.y, w1, fmaf(xa.z, w2, fmaf(xa.w, w3, a0))));
    a1 = fmaf(xb.x, w0, fmaf(xb.y, w1, fmaf(xb.z, w2, fmaf(xb.w, w3, a1))));
    a2 = fmaf(xc.x, w0, fmaf(xc.y, w1, fmaf(xc.z, w2, fmaf(xc.w, w3, a2))));
    a3 = fmaf(xd.x, w0, fmaf(xd.y, w1, fmaf(xd.z, w2, fmaf(xd.w, w3, a3))));
  }
  int row = row0 + rbase;
  if (row + 3 < N) {
    H[(size_t)row * 64 + lane]       = f2bf(a0);
    H[(size_t)(row + 1) * 64 + lane] = f2bf(a1);
    H[(size_t)(row + 2) * 64 + lane] = f2bf(a2);
    H[(size_t)(row + 3) * 64 + lane] = f2bf(a3);
  } else {
    if (row < N)     H[(size_t)row * 64 + lane]       = f2bf(a0);
    if (row + 1 < N) H[(size_t)(row + 1) * 64 + lane] = f2bf(a1);
    if (row + 2 < N) H[(size_t)(row + 2) * 64 + lane] = f2bf(a2);
    if (row + 3 < N) H[(size_t)(row + 3) * 64 + lane] = f2bf(a3);
  }
}

// ---- pass 3: fixed-point hist -> dis/info (x8-PADDED counts); node-sort the
//      bucket slice into csr + pad entries {0,0}; rescale own H rows. ----
__global__ void k_statsfill(const uint2* __restrict__ bucketed,
                            const u32* __restrict__ bucket_cnt,
                            float* __restrict__ dis, int4* __restrict__ info,
                            int2* __restrict__ csr, u16* __restrict__ H, int N) {
  __shared__ u32 hist[BNODES];
  __shared__ u32 cur[BNODES];
  __shared__ float disl[BNODES];
  __shared__ u32 wsum[4];
  int b = blockIdx.x, tid = threadIdx.x;
  for (int i = tid; i < BNODES; i += 256) hist[i] = 0u;
  __syncthreads();
  u32 s0 = (u32)b * CAP, s1 = s0 + bucket_cnt[b];
  for (u32 p = s0 + tid; p < s1; p += 256) {
    uint2 ed = bucketed[p];
    u32 local = ed.x >> SRCBITS;
    u32 wfix = (u32)(__uint_as_float(ed.y) * 262144.0f);   // 18 frac bits
    atomicAdd(&hist[local], (1u << 24) | wfix);            // cnt<<24 | wsum
  }
  __syncthreads();
  u32 h0 = hist[2 * tid], h1 = hist[2 * tid + 1];
  u32 c0 = h0 >> 24, c1 = h1 >> 24;
  u32 p0 = (c0 + 7u) & ~7u, p1 = (c1 + 7u) & ~7u;          // x8-padded counts
  u32 excl = blockscan256_excl(p0 + p1, wsum);
  float d0 = rsqrtf(1.0f + (float)(h0 & 0xFFFFFFu) * (1.0f / 262144.0f));
  float d1 = rsqrtf(1.0f + (float)(h1 & 0xFFFFFFu) * (1.0f / 262144.0f));
  cur[2 * tid] = excl;
  cur[2 * tid + 1] = excl + p0;
  disl[2 * tid] = d0;
  disl[2 * tid + 1] = d1;
  int n0 = b * BNODES + 2 * tid;
  if (n0 < N) {
    dis[n0] = d0;
    info[n0] = make_int4((int)(s0 + excl), (int)p0, __float_as_int(d0), 0);
  }
  if (n0 + 1 < N) {
    dis[n0 + 1] = d1;
    info[n0 + 1] = make_int4((int)(s0 + excl + p0), (int)p1, __float_as_int(d1), 0);
  }
  // pad entries (coef 0, src 0) -- positions never touched by the sort pass
  for (u32 j = c0; j < p0; ++j) csr[s0 + excl + j] = make_int2(0, 0);
  for (u32 j = c1; j < p1; ++j) csr[s0 + excl + p0 + j] = make_int2(0, 0);
  __syncthreads();
  // node-sort the bucket slice (L2-hot re-read), csr = {src, raw w}
  for (u32 p = s0 + tid; p < s1; p += 256) {
    uint2 ed = bucketed[p];
    u32 local = ed.x >> SRCBITS;
    u32 pos = atomicAdd(&cur[local], 1u);
    csr[s0 + pos] = make_int2((int)(ed.x & SRCMASK), (int)ed.y);
  }
  // scale own H rows (H' = dis * H), coalesced uint2 rw
  uint2* Hv = (uint2*)H;
  for (int i = tid; i < BNODES * 16; i += 256) {
    int row = i >> 4;
    int node = b * BNODES + row;
    if (node >= N) break;                  // row monotone per thread
    float dv = disl[row];
    size_t idx = (size_t)node * 16 + (i & 15);
    uint2 v = Hv[idx];
    u32 lo = (u32)f2bf(bf_lo(v.x) * dv) | ((u32)f2bf(bf_hi(v.x) * dv) << 16);
    u32 hi = (u32)f2bf(bf_lo(v.y) * dv) | ((u32)f2bf(bf_hi(v.y) * dv) << 16);
    Hv[idx] = make_uint2(lo, hi);
  }
}

// ---- fused aggregate-1 + GEMM-2: 16 nodes/block, natural order.
// Phase 1: tail-free 8-edge batched gather (x8-padded) -> LDS.
// Phase 2: GEMM from LDS tile, dis epilogue -> h2 bf16.
// LDS 21KB x 7 blocks = 147KB fits -> launch_bounds(256,7), VGPR cap ~73.
__global__ __launch_bounds__(256, 7) void k_agg_gemm(
    const u16* __restrict__ H, const int4* __restrict__ info,
    const int2* __restrict__ csr, const float* __restrict__ bias,
    const float* __restrict__ W2, const float* __restrict__ dis,
    u16* __restrict__ H2, int N) {
  __shared__ float Wt[64 * 65];
  __shared__ float Ys[16 * 64];
  int tid = threadIdx.x;
  for (int i = tid; i < 4096; i += 256) Wt[(i & 63) * 65 + (i >> 6)] = W2[i];
  // ---- phase 1: aggregate 16 nodes ----
  int node = blockIdx.x * 16 + (tid >> 4);
  int fid = (tid & 15) << 2;
  bool valid = node < N;
  int4 nfo = valid ? info[node] : make_int4(0, 0, 0, 0);
  int s0 = nfo.x, n = nfo.y;                        // n is padded (x8)
  float d = __int_as_float(nfo.z);
  uint2 hs = valid ? *(const uint2*)(H + (size_t)node * 64 + fid)
                   : make_uint2(0u, 0u);
  float4 b4 = *(const float4*)(bias + fid);
  float4 acc = make_float4(0.f, 0.f, 0.f, 0.f);
  const int4* c4 = (const int4*)(csr + s0);         // 16B-aligned (x8 padded)
  for (int base = 0; base < n; base += 8)           // tail-free
    AGG8_BODY(c4, base)
  if (valid) {
    acc.x = fmaxf((acc.x + bf_lo(hs.x)) * d + b4.x, 0.f);
    acc.y = fmaxf((acc.y + bf_hi(hs.x)) * d + b4.y, 0.f);
    acc.z = fmaxf((acc.z + bf_lo(hs.y)) * d + b4.z, 0.f);
    acc.w = fmaxf((acc.w + bf_hi(hs.y)) * d + b4.w, 0.f);
  } else {
    acc = make_float4(0.f, 0.f, 0.f, 0.f);
  }
  *(float4*)&Ys[(tid >> 4) * 64 + fid] = acc;       // Y tile -> LDS, not HBM
  __syncthreads();
  // ---- phase 2: GEMM2 from LDS tile ----
  int lane = tid & 63, wv = tid >> 6;
  int rbase = wv * 4;
  int row0 = blockIdx.x * 16;
  float a0 = 0.f, a1 = 0.f, a2 = 0.f, a3 = 0.f;
  #pragma unroll 4
  for (int k4 = 0; k4 < 16; ++k4) {
    int k = k4 << 2;
    float w0 = Wt[k * 65 + lane], w1 = Wt[(k + 1) * 65 + lane];
    float w2 = Wt[(k + 2) * 65 + lane], w3 = Wt[(k + 3) * 65 + lane];
    float4 xa = *(const float4*)&Ys[(rbase + 0) * 64 + k];
    float4 xb = *(const float4*)&Ys[(rbase + 1) * 64 + k];
    float4 xc = *(const float4*)&Ys[(rbase + 2) * 64 + k];
    float4 xd = *(const float4*)&Ys[(rbase + 3) * 64 + k];
    a0 = fmaf(xa.x, w0, fmaf(xa.y, w1, fmaf(xa.z, w2, fmaf(xa.w, w3, a0))));
    a1 = fmaf(xb.x, w0, fmaf(xb.y, w1, fmaf(xb.z, w2, fmaf(xb.w, w3, a1))));
    a2 = fmaf(xc.x, w0, fmaf(xc.y, w1, fmaf(xc.z, w2, fmaf(xc.w, w3, a2))));
    a3 = fmaf(xd.x, w0, fmaf(xd.y, w1, fmaf(xd.z, w2, fmaf(xd.w, w3, a3))));
  }
  int row = row0 + rbase;
  if (row + 3 < N) {
    float dv0 = dis[row], dv1 = dis[row + 1], dv2 = dis[row + 2], dv3 = dis[row + 3];
    H2[(size_t)row * 64 + lane]       = f2bf(a0 * dv0);
    H2[(size_t)(row + 1) * 64 + lane] = f2bf(a1 * dv1);
    H2[(size_t)(row + 2) * 64 + lane] = f2bf(a2 * dv2);
    H2[(size_t)(row + 3) * 64 + lane] = f2bf(a3 * dv3);
  } else {
    if (row < N)     H2[(size_t)row * 64 + lane]       = f2bf(a0 * dis[row]);
    if (row + 1 < N) H2[(size_t)(row + 1) * 64 + lane] = f2bf(a1 * dis[row + 1]);
    if (row + 2 < N) H2[(size_t)(row + 2) * 64 + lane] = f2bf(a2 * dis[row + 2]);
    if (row + 3 < N) H2[(size_t)(row + 3) * 64 + lane] = f2bf(a3 * dis[row + 3]);
  }
}

// ---- final aggregation (layer 2): tail-free 8-edge gather, 32 waves/CU. ----
__global__ __launch_bounds__(256, 8) void k_aggregate2(
    const u16* __restrict__ H, const int4* __restrict__ info,
    const int2* __restrict__ csr, const float* __restrict__ bias,
    float* __restrict__ Y, int N) {
  int tid = threadIdx.x;
  int node = blockIdx.x * 16 + (tid >> 4);
  int fid = (tid & 15) << 2;
  bool valid = node < N;
  int4 nfo = valid ? info[node] : make_int4(0, 0, 0, 0);
  int s0 = nfo.x, n = nfo.y;
  float d = __int_as_float(nfo.z);
  uint2 hs = valid ? *(const uint2*)(H + (size_t)node * 64 + fid)
                   : make_uint2(0u, 0u);
  float4 b4 = *(const float4*)(bias + fid);
  float4 acc = make_float4(0.f, 0.f, 0.f, 0.f);
  const int4* c4 = (const int4*)(csr + s0);
  for (int base = 0; base < n; base += 8)           // tail-free
    AGG8_BODY(c4, base)
  if (valid) {
    acc.x = (acc.x + bf_lo(hs.x)) * d + b4.x;
    acc.y = (acc.y + bf_hi(hs.x)) * d + b4.y;
    acc.z = (acc.z + bf_lo(hs.y)) * d + b4.z;
    acc.w = (acc.w + bf_hi(hs.y)) * d + b4.w;
    *(float4*)(Y + (size_t)node * 64 + fid) = acc;
  }
}

extern "C" void kernel_launch(void* const* d_in, const int* in_sizes, int n_in,
                              void* d_out, int out_size, void* d_ws, size_t ws_size,
                              hipStream_t stream) {
  const float* x  = (const float*)d_in[0];
  const int*   ei = (const int*)d_in[1];
  const float* w  = (const float*)d_in[2];
  const float* W1 = (const float*)d_in[3];
  const float* b1 = (const float*)d_in[4];
  const float* W2 = (const float*)d_in[5];
  const float* b2 = (const float*)d_in[6];
  const int N = in_sizes[0] / 64;
  const int E = in_sizes[2];

  char* ws = (char*)d_ws;
  size_t off = 0;
  auto alloc = [&](size_t bytes) -> char* {
    char* p = ws + off;
    off = (off + bytes + 255) & ~(size_t)255;
    return p;
  };
  u32*   bucket_cnt   = (u32*)  alloc((size_t)NBKT * 4);
  u32*   blockbase    = (u32*)  alloc((size_t)NBKT * 256 * 4);
  uint2* bucketed     = (uint2*)alloc((size_t)NBKT * CAP * 8);
  int2*  csr          = (int2*) alloc((size_t)NBKT * CAP * 8);
  float* dis          = (float*)alloc((size_t)N * 4);
  int4*  info         = (int4*) alloc((size_t)N * 16);
  u16*   h1           = (u16*)  alloc((size_t)N * 64 * 2);
  u16*   h2           = (u16*)  alloc((size_t)N * 64 * 2);

  const int chunk = ((E + 511) / 512) * 2;         // even; 256 blocks cover E
  const int nbG = (N + 15) / 16;                   // 16 rows per GEMM block
  const int nbA = (N + 15) / 16;                   // 16 nodes per agg block
  const int nbB = (N + BNODES - 1) >> LSH;         // 196 buckets

  hipMemsetAsync(bucket_cnt, 0, (size_t)NBKT * 4, stream);
  k_bin<<<256, 256, 0, stream>>>(ei, bucket_cnt, blockbase, E, chunk);
  k_scatter_gemm<<<256 + nbG, 256, 0, stream>>>(ei, w, blockbase, bucketed,
                                                x, W1, h1, N, E, chunk);
  k_statsfill<<<nbB, 256, 0, stream>>>(bucketed, bucket_cnt, dis, info, csr, h1, N);
  k_agg_gemm<<<nbA, 256, 0, stream>>>(h1, info, csr, b1, W2, dis, h2, N);
  k_aggregate2<<<nbA, 256, 0, stream>>>(h2, info, csr, b2, (float*)d_out, N);
}

// Round 10
// 229.887 us; speedup vs baseline: 1.0181x; 1.0181x over previous
//
#include <hip/hip_runtime.h>

// WeightedGCN: 2-layer GCNConv (PyG), N=100K, E=1.25M, D=64, fp32 in/out.
// R19 (base = R17's 230us best; R18's +concurrency bundle = +traffic, no gain:
//  latency is the residual pole, and it's the PER-ITERATION DEPENDENT CHAIN
//  csr-load(~250cy) -> addr -> gather(~500cy) -> fma).
//  Fix: software-pipeline csr one 8-edge batch ahead in registers. Current
//  iteration's gathers start from already-resident csr; next batch's csr loads
//  issue concurrently with gathers+FMAs. Chain/iter ~750 -> ~500 cy.
//  x8 padding (CAP 10240) makes the pipelined loop tail-free; prefetch index
//  clamped to min(base+8, n-8) (last iter reloads, L1-hit). n=0 guard for
//  zero-degree nodes.
//  Configs: k_agg_gemm = R17's proven (256,6); k_aggregate2 = (256,7)
//  (prefetch regs ~56 VGPR fit the 73 cap; (256,8)'s 64 cap risks spill).
// Build pipeline, GEMMs, fusion unchanged from R17.

typedef unsigned int u32;
typedef unsigned short u16;

#define NBKT 256         // coarse buckets
#define LSH 9            // 512 nodes per bucket
#define BNODES 512
#define CAP 10240        // x8-padded capacity (max cnt ~6800 + 7*512 pads)
#define SRCBITS 17       // N=100K < 2^17
#define SRCMASK ((1u << SRCBITS) - 1u)

__device__ inline u16 f2bf(float f) {            // RNE fp32->bf16
  u32 u = __float_as_uint(f);
  u32 r = u + 0x7FFFu + ((u >> 16) & 1u);
  return (u16)(r >> 16);
}
__device__ inline float bf_lo(u32 p) { return __uint_as_float(p << 16); }
__device__ inline float bf_hi(u32 p) { return __uint_as_float(p & 0xFFFF0000u); }

// block-wide (256 thr) exclusive scan of one u32/thread; wsum = LDS[4] scratch.
__device__ inline u32 blockscan256_excl(u32 val, u32* wsum) {
  int lane = threadIdx.x & 63, wv = threadIdx.x >> 6;
  u32 inc = val;
  #pragma unroll
  for (int d = 1; d < 64; d <<= 1) {
    u32 t = __shfl_up(inc, d);
    if (lane >= d) inc += t;
  }
  if (lane == 63) wsum[wv] = inc;
  __syncthreads();
  u32 off = 0;
  #pragma unroll
  for (int i = 0; i < 4; ++i) if (i < wv) off += wsum[i];
  return off + inc - val;
}

// 4-edge FMA burst: gathers already in registers.
#define AGG4(ha, hb, hc, hd, fa, fb, fc, fd)                                   \
  acc.x = fmaf(bf_lo(ha.x), fa, acc.x); acc.y = fmaf(bf_hi(ha.x), fa, acc.y);  \
  acc.z = fmaf(bf_lo(ha.y), fa, acc.z); acc.w = fmaf(bf_hi(ha.y), fa, acc.w);  \
  acc.x = fmaf(bf_lo(hb.x), fb, acc.x); acc.y = fmaf(bf_hi(hb.x), fb, acc.y);  \
  acc.z = fmaf(bf_lo(hb.y), fb, acc.z); acc.w = fmaf(bf_hi(hb.y), fb, acc.w);  \
  acc.x = fmaf(bf_lo(hc.x), fc, acc.x); acc.y = fmaf(bf_hi(hc.x), fc, acc.y);  \
  acc.z = fmaf(bf_lo(hc.y), fc, acc.z); acc.w = fmaf(bf_hi(hc.y), fc, acc.w);  \
  acc.x = fmaf(bf_lo(hd.x), fd, acc.x); acc.y = fmaf(bf_hi(hd.x), fd, acc.y);  \
  acc.z = fmaf(bf_lo(hd.y), fd, acc.z); acc.w = fmaf(bf_hi(hd.y), fd, acc.w);

// Pipelined 8-edge gather loop: csr for batch i+1 prefetched into registers
// while batch i's gathers/FMAs execute. n is x8-padded; n==0 skips entirely.
#define AGG8_PIPE(c4, Hbase, n)                                                \
  if (n > 0) {                                                                 \
    int4 ca = c4[0], cb = c4[1], cc = c4[2], cd = c4[3];                       \
    for (int base = 0; base < n; base += 8) {                                  \
      uint2 h0 = *(const uint2*)(Hbase + (size_t)ca.x * 64 + fid);             \
      uint2 h1 = *(const uint2*)(Hbase + (size_t)ca.z * 64 + fid);             \
      uint2 h2 = *(const uint2*)(Hbase + (size_t)cb.x * 64 + fid);             \
      uint2 h3 = *(const uint2*)(Hbase + (size_t)cb.z * 64 + fid);             \
      uint2 h4 = *(const uint2*)(Hbase + (size_t)cc.x * 64 + fid);             \
      uint2 h5 = *(const uint2*)(Hbase + (size_t)cc.z * 64 + fid);             \
      uint2 h6 = *(const uint2*)(Hbase + (size_t)cd.x * 64 + fid);             \
      uint2 h7 = *(const uint2*)(Hbase + (size_t)cd.z * 64 + fid);             \
      int nxt = min(base + 8, n - 8) >> 1;     /* clamped prefetch index */    \
      int4 na = c4[nxt], nb = c4[nxt + 1];                                     \
      int4 nc2 = c4[nxt + 2], nd = c4[nxt + 3];                                \
      float f0 = __int_as_float(ca.y), f1 = __int_as_float(ca.w);              \
      float f2 = __int_as_float(cb.y), f3 = __int_as_float(cb.w);              \
      float f4 = __int_as_float(cc.y), f5 = __int_as_float(cc.w);              \
      float f6 = __int_as_float(cd.y), f7 = __int_as_float(cd.w);              \
      AGG4(h0, h1, h2, h3, f0, f1, f2, f3)                                     \
      AGG4(h4, h5, h6, h7, f4, f5, f6, f7)                                     \
      ca = na; cb = nb; cc = nc2; cd = nd;                                     \
    }                                                                          \
  }

// ---- pass 1: per-block bucket histogram (LDS atomics) + contiguous range
//      reservation (one global atomicAdd per bucket per block). ----
__global__ void k_bin(const int* __restrict__ ei, u32* __restrict__ bucket_cnt,
                      u32* __restrict__ blockbase, int E, int chunk) {
  __shared__ u32 hist[NBKT];
  if (threadIdx.x < NBKT) hist[threadIdx.x] = 0u;
  __syncthreads();
  int e0 = blockIdx.x * chunk;
  int e1 = min(E, e0 + chunk);
  for (int e = e0 + (threadIdx.x << 1); e < e1; e += 512) {
    if (e + 1 < e1) {
      int2 dd = *(const int2*)(ei + E + e);
      atomicAdd(&hist[dd.x >> LSH], 1u);
      atomicAdd(&hist[dd.y >> LSH], 1u);
    } else {
      atomicAdd(&hist[ei[E + e] >> LSH], 1u);
    }
  }
  __syncthreads();
  if (threadIdx.x < NBKT)
    blockbase[threadIdx.x * 256 + blockIdx.x] =
        atomicAdd(&bucket_cnt[threadIdx.x], hist[threadIdx.x]);
}

// ---- pass 2 (+ fused GEMM-1): scatter edges into reserved bucket sub-ranges.
// GEMM branch (blockIdx >= 256): 16 rows/block, X from LDS, register-lean.
// H1 = X @ W1^T -> bf16 UNSCALED (statsfill scales by dis later).
__global__ __launch_bounds__(256, 4) void k_scatter_gemm(
    const int* __restrict__ ei, const float* __restrict__ w,
    const u32* __restrict__ blockbase,
    uint2* __restrict__ bucketed,
    const float* __restrict__ X, const float* __restrict__ W,
    u16* __restrict__ H, int N, int E, int chunk) {
  __shared__ float Wt[64 * 65];
  __shared__ float Xs[16 * 64];
  __shared__ u32 base[NBKT];
  int tid = threadIdx.x;
  if ((int)blockIdx.x < 256) {
    if (tid < NBKT)
      base[tid] = (u32)tid * CAP + blockbase[tid * 256 + blockIdx.x];
    __syncthreads();
    int e0 = blockIdx.x * chunk, e1 = min(E, e0 + chunk);
    for (int e = e0 + (tid << 1); e < e1; e += 512) {
      if (e + 1 < e1) {
        int2 ss = *(const int2*)(ei + e);
        int2 dd = *(const int2*)(ei + E + e);
        float2 wv = *(const float2*)(w + e);
        u32 p0 = atomicAdd(&base[dd.x >> LSH], 1u);
        u32 p1 = atomicAdd(&base[dd.y >> LSH], 1u);
        bucketed[p0] = make_uint2((u32)ss.x | ((u32)(dd.x & (BNODES - 1)) << SRCBITS),
                                  __float_as_uint(wv.x));
        bucketed[p1] = make_uint2((u32)ss.y | ((u32)(dd.y & (BNODES - 1)) << SRCBITS),
                                  __float_as_uint(wv.y));
      } else {
        int s = ei[e], d = ei[E + e];
        u32 pos = atomicAdd(&base[d >> LSH], 1u);
        bucketed[pos] = make_uint2((u32)s | ((u32)(d & (BNODES - 1)) << SRCBITS),
                                   __float_as_uint(w[e]));
      }
    }
    return;
  }
  // ---- GEMM branch ----
  int row0 = ((int)blockIdx.x - 256) * 16;
  if (row0 >= N) return;
  for (int i = tid; i < 4096; i += 256) Wt[(i & 63) * 65 + (i >> 6)] = W[i];
  {
    const float4* xsrc = (const float4*)(X + (size_t)row0 * 64);
    if (row0 + 16 <= N) {
      ((float4*)Xs)[tid] = xsrc[tid];
    } else {
      int r = tid >> 4;
      ((float4*)Xs)[tid] = (row0 + r < N) ? xsrc[tid]
                                          : make_float4(0.f, 0.f, 0.f, 0.f);
    }
  }
  __syncthreads();
  int lane = tid & 63, wv4 = tid >> 6;
  int rbase = wv4 * 4;
  float a0 = 0.f, a1 = 0.f, a2 = 0.f, a3 = 0.f;
  #pragma unroll 4
  for (int k4 = 0; k4 < 16; ++k4) {
    int k = k4 << 2;
    float w0 = Wt[k * 65 + lane], w1 = Wt[(k + 1) * 65 + lane];
    float w2 = Wt[(k + 2) * 65 + lane], w3 = Wt[(k + 3) * 65 + lane];
    float4 xa = *(const float4*)&Xs[(rbase + 0) * 64 + k];
    float4 xb = *(const float4*)&Xs[(rbase + 1) * 64 + k];
    float4 xc = *(const float4*)&Xs[(rbase + 2) * 64 + k];
    float4 xd = *(const float4*)&Xs[(rbase + 3) * 64 + k];
    a0 = fmaf(xa.x, w0, fmaf(xa.y, w1, fmaf(xa.z, w2, fmaf(xa.w, w3, a0))));
    a1 = fmaf(xb.x, w0, fmaf(xb.y, w1, fmaf(xb.z, w2, fmaf(xb.w, w3, a1))));
    a2 = fmaf(xc.x, w0, fmaf(xc.y, w1, fmaf(xc.z, w2, fmaf(xc.w, w3, a2))));
    a3 = fmaf(xd.x, w0, fmaf(xd.y, w1, fmaf(xd.z, w2, fmaf(xd.w, w3, a3))));
  }
  int row = row0 + rbase;
  if (row + 3 < N) {
    H[(size_t)row * 64 + lane]       = f2bf(a0);
    H[(size_t)(row + 1) * 64 + lane] = f2bf(a1);
    H[(size_t)(row + 2) * 64 + lane] = f2bf(a2);
    H[(size_t)(row + 3) * 64 + lane] = f2bf(a3);
  } else {
    if (row < N)     H[(size_t)row * 64 + lane]       = f2bf(a0);
    if (row + 1 < N) H[(size_t)(row + 1) * 64 + lane] = f2bf(a1);
    if (row + 2 < N) H[(size_t)(row + 2) * 64 + lane] = f2bf(a2);
    if (row + 3 < N) H[(size_t)(row + 3) * 64 + lane] = f2bf(a3);
  }
}

// ---- pass 3: fixed-point hist -> dis/info (x8-PADDED counts); node-sort the
//      bucket slice into csr + pad entries {0,0}; rescale own H rows. ----
__global__ void k_statsfill(const uint2* __restrict__ bucketed,
                            const u32* __restrict__ bucket_cnt,
                            float* __restrict__ dis, int4* __restrict__ info,
                            int2* __restrict__ csr, u16* __restrict__ H, int N) {
  __shared__ u32 hist[BNODES];
  __shared__ u32 cur[BNODES];
  __shared__ float disl[BNODES];
  __shared__ u32 wsum[4];
  int b = blockIdx.x, tid = threadIdx.x;
  for (int i = tid; i < BNODES; i += 256) hist[i] = 0u;
  __syncthreads();
  u32 s0 = (u32)b * CAP, s1 = s0 + bucket_cnt[b];
  for (u32 p = s0 + tid; p < s1; p += 256) {
    uint2 ed = bucketed[p];
    u32 local = ed.x >> SRCBITS;
    u32 wfix = (u32)(__uint_as_float(ed.y) * 262144.0f);   // 18 frac bits
    atomicAdd(&hist[local], (1u << 24) | wfix);            // cnt<<24 | wsum
  }
  __syncthreads();
  u32 h0 = hist[2 * tid], h1 = hist[2 * tid + 1];
  u32 c0 = h0 >> 24, c1 = h1 >> 24;
  u32 p0 = (c0 + 7u) & ~7u, p1 = (c1 + 7u) & ~7u;          // x8-padded counts
  u32 excl = blockscan256_excl(p0 + p1, wsum);
  float d0 = rsqrtf(1.0f + (float)(h0 & 0xFFFFFFu) * (1.0f / 262144.0f));
  float d1 = rsqrtf(1.0f + (float)(h1 & 0xFFFFFFu) * (1.0f / 262144.0f));
  cur[2 * tid] = excl;
  cur[2 * tid + 1] = excl + p0;
  disl[2 * tid] = d0;
  disl[2 * tid + 1] = d1;
  int n0 = b * BNODES + 2 * tid;
  if (n0 < N) {
    dis[n0] = d0;
    info[n0] = make_int4((int)(s0 + excl), (int)p0, __float_as_int(d0), 0);
  }
  if (n0 + 1 < N) {
    dis[n0 + 1] = d1;
    info[n0 + 1] = make_int4((int)(s0 + excl + p0), (int)p1, __float_as_int(d1), 0);
  }
  // pad entries (coef 0, src 0) -- positions never touched by the sort pass
  for (u32 j = c0; j < p0; ++j) csr[s0 + excl + j] = make_int2(0, 0);
  for (u32 j = c1; j < p1; ++j) csr[s0 + excl + p0 + j] = make_int2(0, 0);
  __syncthreads();
  // node-sort the bucket slice (L2-hot re-read), csr = {src, raw w}
  for (u32 p = s0 + tid; p < s1; p += 256) {
    uint2 ed = bucketed[p];
    u32 local = ed.x >> SRCBITS;
    u32 pos = atomicAdd(&cur[local], 1u);
    csr[s0 + pos] = make_int2((int)(ed.x & SRCMASK), (int)ed.y);
  }
  // scale own H rows (H' = dis * H), coalesced uint2 rw
  uint2* Hv = (uint2*)H;
  for (int i = tid; i < BNODES * 16; i += 256) {
    int row = i >> 4;
    int node = b * BNODES + row;
    if (node >= N) break;                  // row monotone per thread
    float dv = disl[row];
    size_t idx = (size_t)node * 16 + (i & 15);
    uint2 v = Hv[idx];
    u32 lo = (u32)f2bf(bf_lo(v.x) * dv) | ((u32)f2bf(bf_hi(v.x) * dv) << 16);
    u32 hi = (u32)f2bf(bf_lo(v.y) * dv) | ((u32)f2bf(bf_hi(v.y) * dv) << 16);
    Hv[idx] = make_uint2(lo, hi);
  }
}

// ---- fused aggregate-1 + GEMM-2: 16 nodes/block, natural order.
// Phase 1: csr-pipelined tail-free 8-edge gather -> LDS.
// Phase 2: GEMM from LDS tile, dis epilogue -> h2 bf16.
__global__ __launch_bounds__(256, 6) void k_agg_gemm(
    const u16* __restrict__ H, const int4* __restrict__ info,
    const int2* __restrict__ csr, const float* __restrict__ bias,
    const float* __restrict__ W2, const float* __restrict__ dis,
    u16* __restrict__ H2, int N) {
  __shared__ float Wt[64 * 65];
  __shared__ float Ys[16 * 64];
  int tid = threadIdx.x;
  for (int i = tid; i < 4096; i += 256) Wt[(i & 63) * 65 + (i >> 6)] = W2[i];
  // ---- phase 1: aggregate 16 nodes ----
  int node = blockIdx.x * 16 + (tid >> 4);
  int fid = (tid & 15) << 2;
  bool valid = node < N;
  int4 nfo = valid ? info[node] : make_int4(0, 0, 0, 0);
  int s0 = nfo.x, n = nfo.y;                        // n is padded (x8)
  float d = __int_as_float(nfo.z);
  uint2 hs = valid ? *(const uint2*)(H + (size_t)node * 64 + fid)
                   : make_uint2(0u, 0u);
  float4 b4 = *(const float4*)(bias + fid);
  float4 acc = make_float4(0.f, 0.f, 0.f, 0.f);
  const int4* c4 = (const int4*)(csr + s0);         // 16B-aligned (x8 padded)
  AGG8_PIPE(c4, H, n)
  if (valid) {
    acc.x = fmaxf((acc.x + bf_lo(hs.x)) * d + b4.x, 0.f);
    acc.y = fmaxf((acc.y + bf_hi(hs.x)) * d + b4.y, 0.f);
    acc.z = fmaxf((acc.z + bf_lo(hs.y)) * d + b4.z, 0.f);
    acc.w = fmaxf((acc.w + bf_hi(hs.y)) * d + b4.w, 0.f);
  } else {
    acc = make_float4(0.f, 0.f, 0.f, 0.f);
  }
  *(float4*)&Ys[(tid >> 4) * 64 + fid] = acc;       // Y tile -> LDS, not HBM
  __syncthreads();
  // ---- phase 2: GEMM2 from LDS tile ----
  int lane = tid & 63, wv = tid >> 6;
  int rbase = wv * 4;
  int row0 = blockIdx.x * 16;
  float a0 = 0.f, a1 = 0.f, a2 = 0.f, a3 = 0.f;
  #pragma unroll 4
  for (int k4 = 0; k4 < 16; ++k4) {
    int k = k4 << 2;
    float w0 = Wt[k * 65 + lane], w1 = Wt[(k + 1) * 65 + lane];
    float w2 = Wt[(k + 2) * 65 + lane], w3 = Wt[(k + 3) * 65 + lane];
    float4 xa = *(const float4*)&Ys[(rbase + 0) * 64 + k];
    float4 xb = *(const float4*)&Ys[(rbase + 1) * 64 + k];
    float4 xc = *(const float4*)&Ys[(rbase + 2) * 64 + k];
    float4 xd = *(const float4*)&Ys[(rbase + 3) * 64 + k];
    a0 = fmaf(xa.x, w0, fmaf(xa.y, w1, fmaf(xa.z, w2, fmaf(xa.w, w3, a0))));
    a1 = fmaf(xb.x, w0, fmaf(xb.y, w1, fmaf(xb.z, w2, fmaf(xb.w, w3, a1))));
    a2 = fmaf(xc.x, w0, fmaf(xc.y, w1, fmaf(xc.z, w2, fmaf(xc.w, w3, a2))));
    a3 = fmaf(xd.x, w0, fmaf(xd.y, w1, fmaf(xd.z, w2, fmaf(xd.w, w3, a3))));
  }
  int row = row0 + rbase;
  if (row + 3 < N) {
    float dv0 = dis[row], dv1 = dis[row + 1], dv2 = dis[row + 2], dv3 = dis[row + 3];
    H2[(size_t)row * 64 + lane]       = f2bf(a0 * dv0);
    H2[(size_t)(row + 1) * 64 + lane] = f2bf(a1 * dv1);
    H2[(size_t)(row + 2) * 64 + lane] = f2bf(a2 * dv2);
    H2[(size_t)(row + 3) * 64 + lane] = f2bf(a3 * dv3);
  } else {
    if (row < N)     H2[(size_t)row * 64 + lane]       = f2bf(a0 * dis[row]);
    if (row + 1 < N) H2[(size_t)(row + 1) * 64 + lane] = f2bf(a1 * dis[row + 1]);
    if (row + 2 < N) H2[(size_t)(row + 2) * 64 + lane] = f2bf(a2 * dis[row + 2]);
    if (row + 3 < N) H2[(size_t)(row + 3) * 64 + lane] = f2bf(a3 * dis[row + 3]);
  }
}

// ---- final aggregation (layer 2): csr-pipelined tail-free 8-edge gather. ----
__global__ __launch_bounds__(256, 7) void k_aggregate2(
    const u16* __restrict__ H, const int4* __restrict__ info,
    const int2* __restrict__ csr, const float* __restrict__ bias,
    float* __restrict__ Y, int N) {
  int tid = threadIdx.x;
  int node = blockIdx.x * 16 + (tid >> 4);
  int fid = (tid & 15) << 2;
  bool valid = node < N;
  int4 nfo = valid ? info[node] : make_int4(0, 0, 0, 0);
  int s0 = nfo.x, n = nfo.y;
  float d = __int_as_float(nfo.z);
  uint2 hs = valid ? *(const uint2*)(H + (size_t)node * 64 + fid)
                   : make_uint2(0u, 0u);
  float4 b4 = *(const float4*)(bias + fid);
  float4 acc = make_float4(0.f, 0.f, 0.f, 0.f);
  const int4* c4 = (const int4*)(csr + s0);
  AGG8_PIPE(c4, H, n)
  if (valid) {
    acc.x = (acc.x + bf_lo(hs.x)) * d + b4.x;
    acc.y = (acc.y + bf_hi(hs.x)) * d + b4.y;
    acc.z = (acc.z + bf_lo(hs.y)) * d + b4.z;
    acc.w = (acc.w + bf_hi(hs.y)) * d + b4.w;
    *(float4*)(Y + (size_t)node * 64 + fid) = acc;
  }
}

extern "C" void kernel_launch(void* const* d_in, const int* in_sizes, int n_in,
                              void* d_out, int out_size, void* d_ws, size_t ws_size,
                              hipStream_t stream) {
  const float* x  = (const float*)d_in[0];
  const int*   ei = (const int*)d_in[1];
  const float* w  = (const float*)d_in[2];
  const float* W1 = (const float*)d_in[3];
  const float* b1 = (const float*)d_in[4];
  const float* W2 = (const float*)d_in[5];
  const float* b2 = (const float*)d_in[6];
  const int N = in_sizes[0] / 64;
  const int E = in_sizes[2];

  char* ws = (char*)d_ws;
  size_t off = 0;
  auto alloc = [&](size_t bytes) -> char* {
    char* p = ws + off;
    off = (off + bytes + 255) & ~(size_t)255;
    return p;
  };
  u32*   bucket_cnt   = (u32*)  alloc((size_t)NBKT * 4);
  u32*   blockbase    = (u32*)  alloc((size_t)NBKT * 256 * 4);
  uint2* bucketed     = (uint2*)alloc((size_t)NBKT * CAP * 8);
  int2*  csr          = (int2*) alloc((size_t)NBKT * CAP * 8);
  float* dis          = (float*)alloc((size_t)N * 4);
  int4*  info         = (int4*) alloc((size_t)N * 16);
  u16*   h1           = (u16*)  alloc((size_t)N * 64 * 2);
  u16*   h2           = (u16*)  alloc((size_t)N * 64 * 2);

  const int chunk = ((E + 511) / 512) * 2;         // even; 256 blocks cover E
  const int nbG = (N + 15) / 16;                   // 16 rows per GEMM block
  const int nbA = (N + 15) / 16;                   // 16 nodes per agg block
  const int nbB = (N + BNODES - 1) >> LSH;         // 196 buckets

  hipMemsetAsync(bucket_cnt, 0, (size_t)NBKT * 4, stream);
  k_bin<<<256, 256, 0, stream>>>(ei, bucket_cnt, blockbase, E, chunk);
  k_scatter_gemm<<<256 + nbG, 256, 0, stream>>>(ei, w, blockbase, bucketed,
                                                x, W1, h1, N, E, chunk);
  k_statsfill<<<nbB, 256, 0, stream>>>(bucketed, bucket_cnt, dis, info, csr, h1, N);
  k_agg_gemm<<<nbA, 256, 0, stream>>>(h1, info, csr, b1, W2, dis, h2, N);
  k_aggregate2<<<nbA, 256, 0, stream>>>(h2, info, csr, b2, (float*)d_out, N);
}